// Round 4
// baseline (408.157 us; speedup 1.0000x reference)
//
#include <hip/hip_runtime.h>

// ---------- bf16 bit helpers ----------
__device__ __forceinline__ float b2f(unsigned short s) {
    union { unsigned int u; float f; } c; c.u = ((unsigned int)s) << 16; return c.f;
}
__device__ __forceinline__ unsigned short f2b(float f) {
    union { float f; unsigned int u; } c; c.f = f;
    unsigned int u = c.u;
    unsigned int r = u + 0x7FFFu + ((u >> 16) & 1u);   // RNE
    return (unsigned short)(r >> 16);
}
__device__ __forceinline__ unsigned int pack2(float lo, float hi) {
    return ((unsigned int)f2b(hi) << 16) | f2b(lo);
}
__device__ __forceinline__ void fma8(float* a, float v, uint4 w) {
    a[0] = fmaf(v, b2f((unsigned short)w.x), a[0]);
    a[1] = fmaf(v, b2f((unsigned short)(w.x >> 16)), a[1]);
    a[2] = fmaf(v, b2f((unsigned short)w.y), a[2]);
    a[3] = fmaf(v, b2f((unsigned short)(w.y >> 16)), a[3]);
    a[4] = fmaf(v, b2f((unsigned short)w.z), a[4]);
    a[5] = fmaf(v, b2f((unsigned short)(w.z >> 16)), a[5]);
    a[6] = fmaf(v, b2f((unsigned short)w.w), a[6]);
    a[7] = fmaf(v, b2f((unsigned short)(w.w >> 16)), a[7]);
}

typedef __attribute__((ext_vector_type(8))) short bf16x8;
typedef __attribute__((ext_vector_type(4))) float f32x4;

#define T_TILES 20

// ---------- K0: detect input dtype (flag=1 -> f32, 0 -> bf16) ----------
__global__ void detect_dtype(const unsigned int* __restrict__ xw, int* __restrict__ flag) {
    __shared__ int c;
    int tid = threadIdx.x;
    if (tid == 0) c = 0;
    __syncthreads();
    int cnt = 0;
    for (int i = tid; i < 1024; i += 256) {
        unsigned int w = xw[i];
        unsigned int e = (w >> 7) & 0xFFu;   // exponent of LOW half viewed as bf16
        if (e >= 0x90u) cnt++;               // |v| >= 2^17: impossible for N(0,1) bf16
    }
    atomicAdd(&c, cnt);
    __syncthreads();
    if (tid == 0) flag[0] = (c > 100) ? 1 : 0;
}

// ---------- K1: fused prep: rowptr | param conv | x/x_tilde -> interleaved bf16 ----------
// xint layout: node row = 512 B: [x 128 bf16][x_tilde 128 bf16]
__global__ __launch_bounds__(256) void prep(
    const int* __restrict__ row, int* __restrict__ rp, int n, int e, int rb,
    const void* __restrict__ w1, const void* __restrict__ wbil,
    const void* __restrict__ pa, const int* __restrict__ flag,
    unsigned short* __restrict__ w1b, float* __restrict__ wbilf, float* __restrict__ paf,
    int pb,
    const void* __restrict__ x, const void* __restrict__ xt,
    unsigned short* __restrict__ xint, int total8, int halfcb)
{
    int b = blockIdx.x, tid = threadIdx.x;
    if (b < rb) {                                   // --- build row_ptr ---
        int i = b * 256 + tid;
        if (i > e) return;
        if (i == 0) {
            int r1 = row[0];
            for (int rr = 0; rr <= r1; ++rr) rp[rr] = 0;
        } else if (i == e) {
            int r0 = row[e - 1];
            for (int rr = r0 + 1; rr <= n; ++rr) rp[rr] = e;
        } else {
            int r0 = row[i - 1], r1 = row[i];
            for (int rr = r0 + 1; rr <= r1; ++rr) rp[rr] = i;
        }
    } else if (b < rb + pb) {                       // --- param conversion ---
        int i = (b - rb) * 256 + tid;               // 0..65535
        if (flag[0]) {
            if (i < 32768) w1b[i] = f2b(((const float*)w1)[i]);
            wbilf[i] = ((const float*)wbil)[i];
            if (i == 0) paf[0] = ((const float*)pa)[0];
        } else {
            if (i < 32768) w1b[i] = ((const unsigned short*)w1)[i];
            wbilf[i] = b2f(((const unsigned short*)wbil)[i]);
            if (i == 0) paf[0] = b2f(((const unsigned short*)pa)[0]);
        }
    } else {                                        // --- x conversion (interleaved) ---
        int cb = b - rb - pb;
        int which = (cb >= halfcb) ? 1 : 0;
        int i = (cb - which * halfcb) * 256 + tid;  // 8-elem chunk index
        if (i >= total8) return;
        const void* s = which ? xt : x;
        int node = i >> 4, sub = i & 15;
        uint4 o;
        if (flag[0]) {
            const float4* p = (const float4*)s + (size_t)i * 2;
            float4 a = p[0], bb = p[1];
            o.x = pack2(a.x, a.y);  o.y = pack2(a.z, a.w);
            o.z = pack2(bb.x, bb.y); o.w = pack2(bb.z, bb.w);
        } else {
            o = ((const uint4*)s)[i];
        }
        *(uint4*)(xint + (size_t)node * 256 + which * 128 + sub * 8) = o;
    }
}

// ---------- K2: dual SpMM on interleaved bf16; 4 edge-groups/wave, 2x unroll ----------
__global__ __launch_bounds__(256) void spmm_dual3(
    const unsigned short* __restrict__ xint, const void* __restrict__ valsv,
    const int* __restrict__ col, const int* __restrict__ row_ptr,
    const int* __restrict__ flag,
    unsigned short* __restrict__ aggx, unsigned short* __restrict__ aggt, int n)
{
    int wave = threadIdx.x >> 6;
    int lane = threadIdx.x & 63;
    int g = lane >> 4, l = lane & 15;
    int r = blockIdx.x * 4 + wave;
    if (r >= n) return;
    int e0 = row_ptr[r], e1 = row_ptr[r + 1];
    float ax[8], at[8];
#pragma unroll
    for (int d = 0; d < 8; ++d) { ax[d] = 0.f; at[d] = 0.f; }
    if (flag[0]) {
        const float* vals = (const float*)valsv;
        for (int base = e0; base < e1; base += 8) {
            int eA = base + g, eB = base + 4 + g;
            bool vA = eA < e1, vB = eB < e1;
            int ecA = vA ? eA : e1 - 1, ecB = vB ? eB : e1 - 1;
            int cA = col[ecA], cB = col[ecB];
            float fvA = vA ? vals[ecA] : 0.f;
            float fvB = vB ? vals[ecB] : 0.f;
            const uint4* pA = (const uint4*)(xint + (size_t)cA * 256);
            const uint4* pB = (const uint4*)(xint + (size_t)cB * 256);
            uint4 xA = pA[l], tA = pA[16 + l];
            uint4 xB = pB[l], tB = pB[16 + l];
            fma8(ax, fvA, xA); fma8(at, fvA, tA);
            fma8(ax, fvB, xB); fma8(at, fvB, tB);
        }
    } else {
        const unsigned short* vals = (const unsigned short*)valsv;
        for (int base = e0; base < e1; base += 8) {
            int eA = base + g, eB = base + 4 + g;
            bool vA = eA < e1, vB = eB < e1;
            int ecA = vA ? eA : e1 - 1, ecB = vB ? eB : e1 - 1;
            int cA = col[ecA], cB = col[ecB];
            float fvA = vA ? b2f(vals[ecA]) : 0.f;
            float fvB = vB ? b2f(vals[ecB]) : 0.f;
            const uint4* pA = (const uint4*)(xint + (size_t)cA * 256);
            const uint4* pB = (const uint4*)(xint + (size_t)cB * 256);
            uint4 xA = pA[l], tA = pA[16 + l];
            uint4 xB = pB[l], tB = pB[16 + l];
            fma8(ax, fvA, xA); fma8(at, fvA, tA);
            fma8(ax, fvB, xB); fma8(at, fvB, tB);
        }
    }
#pragma unroll
    for (int d = 0; d < 8; ++d) {
        ax[d] += __shfl_xor(ax[d], 16, 64);
        ax[d] += __shfl_xor(ax[d], 32, 64);
        at[d] += __shfl_xor(at[d], 16, 64);
        at[d] += __shfl_xor(at[d], 32, 64);
    }
    if (g == 0) {
        uint4 o;
        o.x = pack2(ax[0], ax[1]); o.y = pack2(ax[2], ax[3]);
        o.z = pack2(ax[4], ax[5]); o.w = pack2(ax[6], ax[7]);
        ((uint4*)(aggx + (size_t)r * 128))[l] = o;
    } else if (g == 1) {
        uint4 o;
        o.x = pack2(at[0], at[1]); o.y = pack2(at[2], at[3]);
        o.z = pack2(at[4], at[5]); o.w = pack2(at[6], at[7]);
        ((uint4*)(aggt + (size_t)r * 128))[l] = o;
    }
}

// ---------- K2b: legacy SpMM (raw f32/bf16 gather) — ws-too-small fallback ----------
__global__ __launch_bounds__(256) void spmm_dual_legacy(
    const void* __restrict__ xv, const void* __restrict__ xtv,
    const void* __restrict__ valsv, const int* __restrict__ col,
    const int* __restrict__ row_ptr, const int* __restrict__ flag,
    unsigned short* __restrict__ aggx, unsigned short* __restrict__ aggt, int n)
{
    int wave = threadIdx.x >> 6;
    int lane = threadIdx.x & 63;
    int r = blockIdx.x * 4 + wave;
    if (r >= n) return;
    int e0 = row_ptr[r], e1 = row_ptr[r + 1];
    float ax0 = 0.f, ax1 = 0.f, at0 = 0.f, at1 = 0.f;
    if (flag[0]) {
        const float* x  = (const float*)xv;
        const float* xt = (const float*)xtv;
        const float* vals = (const float*)valsv;
        for (int e = e0; e < e1; ++e) {
            int c = col[e];
            float v = vals[e];
            float2 wx = ((const float2*)(x + (size_t)c * 128))[lane];
            float2 wt = ((const float2*)(xt + (size_t)c * 128))[lane];
            ax0 = fmaf(v, wx.x, ax0); ax1 = fmaf(v, wx.y, ax1);
            at0 = fmaf(v, wt.x, at0); at1 = fmaf(v, wt.y, at1);
        }
    } else {
        const unsigned short* x  = (const unsigned short*)xv;
        const unsigned short* xt = (const unsigned short*)xtv;
        const unsigned short* vals = (const unsigned short*)valsv;
        for (int e = e0; e < e1; ++e) {
            int c = col[e];
            float v = b2f(vals[e]);
            unsigned int wx = ((const unsigned int*)(x + (size_t)c * 128))[lane];
            unsigned int wt = ((const unsigned int*)(xt + (size_t)c * 128))[lane];
            ax0 = fmaf(v, b2f((unsigned short)wx), ax0);
            ax1 = fmaf(v, b2f((unsigned short)(wx >> 16)), ax1);
            at0 = fmaf(v, b2f((unsigned short)wt), at0);
            at1 = fmaf(v, b2f((unsigned short)(wt >> 16)), at1);
        }
    }
    ((unsigned int*)(aggx + (size_t)r * 128))[lane] = pack2(ax0, ax1);
    ((unsigned int*)(aggt + (size_t)r * 128))[lane] = pack2(at0, at1);
}

// ---------- K3: GEMM + colsum; W1 resident in regs; atomic-free partials ----------
// C/D layout: col = nl, row = quad*4 + r. Column sum => sum over r, then quad bits.
__global__ __launch_bounds__(256) void gemm_colsum3(
    const short* __restrict__ aggb, const short* __restrict__ w1,
    const float* __restrict__ paf, float* __restrict__ partial, int ntiles)
{
    int tid = threadIdx.x;
    int w = tid >> 6, lane = tid & 63;
    int nl = lane & 15, quad = lane >> 4;
    const short* brow = w1 + ((size_t)(4 * w) * 16 + nl) * 128 + quad * 8;
    bf16x8 bf[4][4];
#pragma unroll
    for (int j = 0; j < 4; ++j)
#pragma unroll
        for (int k = 0; k < 4; ++k)
            bf[j][k] = *(const bf16x8*)(brow + j * 2048 + k * 32);
    float aslope = paf[0];
    float cs[4] = {0.f, 0.f, 0.f, 0.f};
    int t0 = blockIdx.x * T_TILES;
    int nt = ntiles - t0; if (nt > T_TILES) nt = T_TILES;
    for (int i = 0; i < nt; ++i) {
        const short* arow = aggb + ((size_t)(t0 + i) * 16 + nl) * 128 + quad * 8;
        bf16x8 af[4];
#pragma unroll
        for (int k = 0; k < 4; ++k) af[k] = *(const bf16x8*)(arow + k * 32);
        f32x4 acc[4];
#pragma unroll
        for (int j = 0; j < 4; ++j) acc[j] = (f32x4){0.f, 0.f, 0.f, 0.f};
#pragma unroll
        for (int k = 0; k < 4; ++k)
#pragma unroll
            for (int j = 0; j < 4; ++j)
                acc[j] = __builtin_amdgcn_mfma_f32_16x16x32_bf16(af[k], bf[j][k], acc[j], 0, 0, 0);
#pragma unroll
        for (int j = 0; j < 4; ++j)
#pragma unroll
            for (int r = 0; r < 4; ++r) {
                float z = acc[j][r];
                cs[j] += (z >= 0.f) ? z : aslope * z;
            }
    }
#pragma unroll
    for (int j = 0; j < 4; ++j) {
        cs[j] += __shfl_xor(cs[j], 16, 64);   // reduce rows: quad bits only
        cs[j] += __shfl_xor(cs[j], 32, 64);
    }
    if (quad == 0)
#pragma unroll
        for (int j = 0; j < 4; ++j)
            partial[(size_t)blockIdx.x * 256 + (4 * w + j) * 16 + nl] = cs[j];
}

// ---------- K4: reduce partials -> sigmoid -> v = w_bil @ s ----------
__global__ __launch_bounds__(256) void compute_v2(
    const float* __restrict__ partial, int nblocks,
    const float* __restrict__ wbilf, float* __restrict__ v, float invN)
{
    __shared__ float s_lds[256];
    int t = threadIdx.x;
    float s = 0.f;
    for (int b = 0; b < nblocks; ++b)
        s += partial[(size_t)b * 256 + t];
    s_lds[t] = 1.f / (1.f + expf(-s * invN));
    __syncthreads();
    const float* wrow = wbilf + (size_t)t * 256;
    float acc = 0.f;
#pragma unroll 8
    for (int j = 0; j < 256; ++j)
        acc = fmaf(wrow[j], s_lds[j], acc);
    v[t] = acc;
}

// ---------- K5: GEMM + dot with v; W1 resident; LDS cross-wave reduce ----------
__global__ __launch_bounds__(256) void gemm_dp2(
    const short* __restrict__ aggx, const short* __restrict__ aggt,
    const short* __restrict__ w1, const float* __restrict__ paf,
    const float* __restrict__ v, const int* __restrict__ flag,
    void* __restrict__ outv, int ntiles, int N)
{
    __shared__ float dpbuf[4][T_TILES * 16];
    int tid = threadIdx.x;
    int w = tid >> 6, lane = tid & 63;
    int nl = lane & 15, quad = lane >> 4;
    const short* agg = blockIdx.y ? aggt : aggx;
    const short* brow = w1 + ((size_t)(4 * w) * 16 + nl) * 128 + quad * 8;
    bf16x8 bf[4][4];
#pragma unroll
    for (int j = 0; j < 4; ++j)
#pragma unroll
        for (int k = 0; k < 4; ++k)
            bf[j][k] = *(const bf16x8*)(brow + j * 2048 + k * 32);
    float vreg[4];
#pragma unroll
    for (int j = 0; j < 4; ++j) vreg[j] = v[(4 * w + j) * 16 + nl];
    float aslope = paf[0];
    int t0 = blockIdx.x * T_TILES;
    int nt = ntiles - t0; if (nt > T_TILES) nt = T_TILES;
    for (int i = 0; i < nt; ++i) {
        const short* arow = agg + ((size_t)(t0 + i) * 16 + nl) * 128 + quad * 8;
        bf16x8 af[4];
#pragma unroll
        for (int k = 0; k < 4; ++k) af[k] = *(const bf16x8*)(arow + k * 32);
        f32x4 acc[4];
#pragma unroll
        for (int j = 0; j < 4; ++j) acc[j] = (f32x4){0.f, 0.f, 0.f, 0.f};
#pragma unroll
        for (int k = 0; k < 4; ++k)
#pragma unroll
            for (int j = 0; j < 4; ++j)
                acc[j] = __builtin_amdgcn_mfma_f32_16x16x32_bf16(af[k], bf[j][k], acc[j], 0, 0, 0);
        float p[4] = {0.f, 0.f, 0.f, 0.f};
#pragma unroll
        for (int j = 0; j < 4; ++j)
#pragma unroll
            for (int r = 0; r < 4; ++r) {
                float z = acc[j][r];
                float h = (z >= 0.f) ? z : aslope * z;
                p[r] = fmaf(h, vreg[j], p[r]);
            }
#pragma unroll
        for (int r = 0; r < 4; ++r) {   // reduce over nl bits (16 cols of the slice)
            p[r] += __shfl_xor(p[r], 1, 64);
            p[r] += __shfl_xor(p[r], 2, 64);
            p[r] += __shfl_xor(p[r], 4, 64);
            p[r] += __shfl_xor(p[r], 8, 64);
        }
        if (nl == 0)
#pragma unroll
            for (int r = 0; r < 4; ++r)
                dpbuf[w][i * 16 + quad * 4 + r] = p[r];
    }
    __syncthreads();
    int nloc = nt * 16;
    int f = flag[0];
    for (int idx = tid; idx < nloc; idx += 256) {
        float s = dpbuf[0][idx] + dpbuf[1][idx] + dpbuf[2][idx] + dpbuf[3][idx];
        size_t o = (size_t)blockIdx.y * N + (size_t)t0 * 16 + idx;
        if (f) ((float*)outv)[o] = s;
        else   ((unsigned short*)outv)[o] = f2b(s);
    }
}

extern "C" void kernel_launch(void* const* d_in, const int* in_sizes, int n_in,
                              void* d_out, int out_size, void* d_ws, size_t ws_size,
                              hipStream_t stream) {
    const void* x    = d_in[0];
    const void* xt   = d_in[1];
    const void* vals = d_in[2];
    const int* row   = (const int*)d_in[3];
    const int* col   = (const int*)d_in[4];
    const void* w1   = d_in[5];
    const void* pa   = d_in[6];
    const void* wb   = d_in[7];

    const int N = in_sizes[0] / 128;
    const int E = in_sizes[2];
    const int ntiles = (N + 15) / 16;
    const int cs_blocks = (ntiles + T_TILES - 1) / T_TILES;

    char* ws = (char*)d_ws;
    size_t off = 0;
    auto alloc = [&](size_t bytes) { char* p = ws + off; off = (off + bytes + 255) & ~(size_t)255; return p; };
    int* row_ptr         = (int*)alloc((size_t)(N + 1) * 4);
    unsigned short* aggx = (unsigned short*)alloc((size_t)N * 128 * 2);
    unsigned short* aggt = (unsigned short*)alloc((size_t)N * 128 * 2);
    unsigned short* w1b  = (unsigned short*)alloc(32768 * 2);
    float* wbilf         = (float*)alloc(65536 * 4);
    float* partial       = (float*)alloc((size_t)cs_blocks * 256 * 4);
    float* vvec          = (float*)alloc(256 * 4);
    float* paf           = (float*)alloc(4);
    int* flag            = (int*)alloc(4);
    size_t xintBytes = (size_t)N * 256 * 2;   // interleaved x | x_tilde (bf16)
    bool big = (off + xintBytes + 512) <= ws_size;
    unsigned short* xint = nullptr;
    if (big) xint = (unsigned short*)alloc(xintBytes);

    detect_dtype<<<1, 256, 0, stream>>>((const unsigned int*)x, flag);

    int rb = (E + 1 + 255) / 256;
    int pb = 256;
    int total8 = (N * 128) / 8;
    int halfcb = big ? (total8 + 255) / 256 : 0;
    prep<<<rb + pb + 2 * halfcb, 256, 0, stream>>>(
        row, row_ptr, N, E, rb,
        w1, wb, pa, flag, w1b, wbilf, paf, pb,
        x, xt, xint, total8, halfcb);

    if (big) {
        spmm_dual3<<<(N + 3) / 4, 256, 0, stream>>>(xint, vals, col, row_ptr, flag,
                                                    aggx, aggt, N);
    } else {
        spmm_dual_legacy<<<(N + 3) / 4, 256, 0, stream>>>(x, xt, vals, col, row_ptr, flag,
                                                          aggx, aggt, N);
    }
    gemm_colsum3<<<cs_blocks, 256, 0, stream>>>(
        (const short*)aggx, (const short*)w1b, paf, partial, ntiles);
    compute_v2<<<1, 256, 0, stream>>>(partial, cs_blocks, wbilf, vvec, 1.0f / (float)N);
    gemm_dp2<<<dim3(cs_blocks, 2), 256, 0, stream>>>(
        (const short*)aggx, (const short*)aggt, (const short*)w1b, paf, vvec, flag,
        d_out, ntiles, N);
}

// Round 5
// 340.570 us; speedup vs baseline: 1.1985x; 1.1985x over previous
//
#include <hip/hip_runtime.h>

// ---------- bf16 bit helpers ----------
__device__ __forceinline__ float b2f(unsigned short s) {
    union { unsigned int u; float f; } c; c.u = ((unsigned int)s) << 16; return c.f;
}
__device__ __forceinline__ unsigned short f2b(float f) {
    union { float f; unsigned int u; } c; c.f = f;
    unsigned int u = c.u;
    unsigned int r = u + 0x7FFFu + ((u >> 16) & 1u);   // RNE
    return (unsigned short)(r >> 16);
}
__device__ __forceinline__ unsigned int pack2(float lo, float hi) {
    return ((unsigned int)f2b(hi) << 16) | f2b(lo);
}
__device__ __forceinline__ void fma8(float* a, float v, uint4 w) {
    a[0] = fmaf(v, b2f((unsigned short)w.x), a[0]);
    a[1] = fmaf(v, b2f((unsigned short)(w.x >> 16)), a[1]);
    a[2] = fmaf(v, b2f((unsigned short)w.y), a[2]);
    a[3] = fmaf(v, b2f((unsigned short)(w.y >> 16)), a[3]);
    a[4] = fmaf(v, b2f((unsigned short)w.z), a[4]);
    a[5] = fmaf(v, b2f((unsigned short)(w.z >> 16)), a[5]);
    a[6] = fmaf(v, b2f((unsigned short)w.w), a[6]);
    a[7] = fmaf(v, b2f((unsigned short)(w.w >> 16)), a[7]);
}

typedef __attribute__((ext_vector_type(8))) short bf16x8;
typedef __attribute__((ext_vector_type(4))) float f32x4;

#define T_TILES 10

// ---------- K0: detect input dtype (flag=1 -> f32, 0 -> bf16) ----------
__global__ void detect_dtype(const unsigned int* __restrict__ xw, int* __restrict__ flag) {
    __shared__ int c;
    int tid = threadIdx.x;
    if (tid == 0) c = 0;
    __syncthreads();
    int cnt = 0;
    for (int i = tid; i < 1024; i += 256) {
        unsigned int w = xw[i];
        unsigned int e = (w >> 7) & 0xFFu;   // exponent of LOW half viewed as bf16
        if (e >= 0x90u) cnt++;               // |v| >= 2^17: impossible for N(0,1) bf16
    }
    atomicAdd(&c, cnt);
    __syncthreads();
    if (tid == 0) flag[0] = (c > 100) ? 1 : 0;
}

// ---------- K1: fused prep: rowptr | param conv | x/x_tilde -> interleaved bf16 ----------
// xint layout: node row = 512 B: [x 128 bf16][x_tilde 128 bf16]
__global__ __launch_bounds__(256) void prep(
    const int* __restrict__ row, int* __restrict__ rp, int n, int e, int rb,
    const void* __restrict__ w1, const void* __restrict__ wbil,
    const void* __restrict__ pa, const int* __restrict__ flag,
    unsigned short* __restrict__ w1b, float* __restrict__ wbilf, float* __restrict__ paf,
    int pb,
    const void* __restrict__ x, const void* __restrict__ xt,
    unsigned short* __restrict__ xint, int total8, int halfcb)
{
    int b = blockIdx.x, tid = threadIdx.x;
    if (b < rb) {                                   // --- build row_ptr ---
        int i = b * 256 + tid;
        if (i > e) return;
        if (i == 0) {
            int r1 = row[0];
            for (int rr = 0; rr <= r1; ++rr) rp[rr] = 0;
        } else if (i == e) {
            int r0 = row[e - 1];
            for (int rr = r0 + 1; rr <= n; ++rr) rp[rr] = e;
        } else {
            int r0 = row[i - 1], r1 = row[i];
            for (int rr = r0 + 1; rr <= r1; ++rr) rp[rr] = i;
        }
    } else if (b < rb + pb) {                       // --- param conversion ---
        int i = (b - rb) * 256 + tid;               // 0..65535
        if (flag[0]) {
            if (i < 32768) w1b[i] = f2b(((const float*)w1)[i]);
            wbilf[i] = ((const float*)wbil)[i];
            if (i == 0) paf[0] = ((const float*)pa)[0];
        } else {
            if (i < 32768) w1b[i] = ((const unsigned short*)w1)[i];
            wbilf[i] = b2f(((const unsigned short*)wbil)[i]);
            if (i == 0) paf[0] = b2f(((const unsigned short*)pa)[0]);
        }
    } else {                                        // --- x conversion (interleaved) ---
        int cb = b - rb - pb;
        int which = (cb >= halfcb) ? 1 : 0;
        int i = (cb - which * halfcb) * 256 + tid;  // 8-elem chunk index
        if (i >= total8) return;
        const void* s = which ? xt : x;
        int node = i >> 4, sub = i & 15;
        uint4 o;
        if (flag[0]) {
            const float4* p = (const float4*)s + (size_t)i * 2;
            float4 a = p[0], bb = p[1];
            o.x = pack2(a.x, a.y);  o.y = pack2(a.z, a.w);
            o.z = pack2(bb.x, bb.y); o.w = pack2(bb.z, bb.w);
        } else {
            o = ((const uint4*)s)[i];
        }
        *(uint4*)(xint + (size_t)node * 256 + which * 128 + sub * 8) = o;
    }
}

// ---------- K2: dual SpMM on interleaved bf16; 4 edge-groups/wave, 2x unroll ----------
__global__ __launch_bounds__(256) void spmm_dual3(
    const unsigned short* __restrict__ xint, const void* __restrict__ valsv,
    const int* __restrict__ col, const int* __restrict__ row_ptr,
    const int* __restrict__ flag,
    unsigned short* __restrict__ aggx, unsigned short* __restrict__ aggt, int n)
{
    int wave = threadIdx.x >> 6;
    int lane = threadIdx.x & 63;
    int g = lane >> 4, l = lane & 15;
    int r = blockIdx.x * 4 + wave;
    if (r >= n) return;
    int e0 = row_ptr[r], e1 = row_ptr[r + 1];
    float ax[8], at[8];
#pragma unroll
    for (int d = 0; d < 8; ++d) { ax[d] = 0.f; at[d] = 0.f; }
    if (flag[0]) {
        const float* vals = (const float*)valsv;
        for (int base = e0; base < e1; base += 8) {
            int eA = base + g, eB = base + 4 + g;
            bool vA = eA < e1, vB = eB < e1;
            int ecA = vA ? eA : e1 - 1, ecB = vB ? eB : e1 - 1;
            int cA = col[ecA], cB = col[ecB];
            float fvA = vA ? vals[ecA] : 0.f;
            float fvB = vB ? vals[ecB] : 0.f;
            const uint4* pA = (const uint4*)(xint + (size_t)cA * 256);
            const uint4* pB = (const uint4*)(xint + (size_t)cB * 256);
            uint4 xA = pA[l], tA = pA[16 + l];
            uint4 xB = pB[l], tB = pB[16 + l];
            fma8(ax, fvA, xA); fma8(at, fvA, tA);
            fma8(ax, fvB, xB); fma8(at, fvB, tB);
        }
    } else {
        const unsigned short* vals = (const unsigned short*)valsv;
        for (int base = e0; base < e1; base += 8) {
            int eA = base + g, eB = base + 4 + g;
            bool vA = eA < e1, vB = eB < e1;
            int ecA = vA ? eA : e1 - 1, ecB = vB ? eB : e1 - 1;
            int cA = col[ecA], cB = col[ecB];
            float fvA = vA ? b2f(vals[ecA]) : 0.f;
            float fvB = vB ? b2f(vals[ecB]) : 0.f;
            const uint4* pA = (const uint4*)(xint + (size_t)cA * 256);
            const uint4* pB = (const uint4*)(xint + (size_t)cB * 256);
            uint4 xA = pA[l], tA = pA[16 + l];
            uint4 xB = pB[l], tB = pB[16 + l];
            fma8(ax, fvA, xA); fma8(at, fvA, tA);
            fma8(ax, fvB, xB); fma8(at, fvB, tB);
        }
    }
#pragma unroll
    for (int d = 0; d < 8; ++d) {
        ax[d] += __shfl_xor(ax[d], 16, 64);
        ax[d] += __shfl_xor(ax[d], 32, 64);
        at[d] += __shfl_xor(at[d], 16, 64);
        at[d] += __shfl_xor(at[d], 32, 64);
    }
    if (g == 0) {
        uint4 o;
        o.x = pack2(ax[0], ax[1]); o.y = pack2(ax[2], ax[3]);
        o.z = pack2(ax[4], ax[5]); o.w = pack2(ax[6], ax[7]);
        ((uint4*)(aggx + (size_t)r * 128))[l] = o;
    } else if (g == 1) {
        uint4 o;
        o.x = pack2(at[0], at[1]); o.y = pack2(at[2], at[3]);
        o.z = pack2(at[4], at[5]); o.w = pack2(at[6], at[7]);
        ((uint4*)(aggt + (size_t)r * 128))[l] = o;
    }
}

// ---------- K2b: legacy SpMM (raw f32/bf16 gather) — ws-too-small fallback ----------
__global__ __launch_bounds__(256) void spmm_dual_legacy(
    const void* __restrict__ xv, const void* __restrict__ xtv,
    const void* __restrict__ valsv, const int* __restrict__ col,
    const int* __restrict__ row_ptr, const int* __restrict__ flag,
    unsigned short* __restrict__ aggx, unsigned short* __restrict__ aggt, int n)
{
    int wave = threadIdx.x >> 6;
    int lane = threadIdx.x & 63;
    int r = blockIdx.x * 4 + wave;
    if (r >= n) return;
    int e0 = row_ptr[r], e1 = row_ptr[r + 1];
    float ax0 = 0.f, ax1 = 0.f, at0 = 0.f, at1 = 0.f;
    if (flag[0]) {
        const float* x  = (const float*)xv;
        const float* xt = (const float*)xtv;
        const float* vals = (const float*)valsv;
        for (int e = e0; e < e1; ++e) {
            int c = col[e];
            float v = vals[e];
            float2 wx = ((const float2*)(x + (size_t)c * 128))[lane];
            float2 wt = ((const float2*)(xt + (size_t)c * 128))[lane];
            ax0 = fmaf(v, wx.x, ax0); ax1 = fmaf(v, wx.y, ax1);
            at0 = fmaf(v, wt.x, at0); at1 = fmaf(v, wt.y, at1);
        }
    } else {
        const unsigned short* x  = (const unsigned short*)xv;
        const unsigned short* xt = (const unsigned short*)xtv;
        const unsigned short* vals = (const unsigned short*)valsv;
        for (int e = e0; e < e1; ++e) {
            int c = col[e];
            float v = b2f(vals[e]);
            unsigned int wx = ((const unsigned int*)(x + (size_t)c * 128))[lane];
            unsigned int wt = ((const unsigned int*)(xt + (size_t)c * 128))[lane];
            ax0 = fmaf(v, b2f((unsigned short)wx), ax0);
            ax1 = fmaf(v, b2f((unsigned short)(wx >> 16)), ax1);
            at0 = fmaf(v, b2f((unsigned short)wt), at0);
            at1 = fmaf(v, b2f((unsigned short)(wt >> 16)), at1);
        }
    }
    ((unsigned int*)(aggx + (size_t)r * 128))[lane] = pack2(ax0, ax1);
    ((unsigned int*)(aggt + (size_t)r * 128))[lane] = pack2(at0, at1);
}

// ---------- K3: GEMM + colsum; W1 resident; transposed atomic-free partials ----------
// C/D layout: col = nl, row = quad*4 + r. Column sum => sum over r, then quad bits.
// partial layout: [out_dim 256][block nb]  (coalesced for the reducer)
__global__ __launch_bounds__(256) void gemm_colsum3(
    const short* __restrict__ aggb, const short* __restrict__ w1,
    const float* __restrict__ paf, float* __restrict__ partial, int ntiles, int nb)
{
    int tid = threadIdx.x;
    int w = tid >> 6, lane = tid & 63;
    int nl = lane & 15, quad = lane >> 4;
    const short* brow = w1 + ((size_t)(4 * w) * 16 + nl) * 128 + quad * 8;
    bf16x8 bf[4][4];
#pragma unroll
    for (int j = 0; j < 4; ++j)
#pragma unroll
        for (int k = 0; k < 4; ++k)
            bf[j][k] = *(const bf16x8*)(brow + j * 2048 + k * 32);
    float aslope = paf[0];
    float cs[4] = {0.f, 0.f, 0.f, 0.f};
    int t0 = blockIdx.x * T_TILES;
    int nt = ntiles - t0; if (nt > T_TILES) nt = T_TILES;
    for (int i = 0; i < nt; ++i) {
        const short* arow = aggb + ((size_t)(t0 + i) * 16 + nl) * 128 + quad * 8;
        bf16x8 af[4];
#pragma unroll
        for (int k = 0; k < 4; ++k) af[k] = *(const bf16x8*)(arow + k * 32);
        f32x4 acc[4];
#pragma unroll
        for (int j = 0; j < 4; ++j) acc[j] = (f32x4){0.f, 0.f, 0.f, 0.f};
#pragma unroll
        for (int k = 0; k < 4; ++k)
#pragma unroll
            for (int j = 0; j < 4; ++j)
                acc[j] = __builtin_amdgcn_mfma_f32_16x16x32_bf16(af[k], bf[j][k], acc[j], 0, 0, 0);
#pragma unroll
        for (int j = 0; j < 4; ++j)
#pragma unroll
            for (int r = 0; r < 4; ++r) {
                float z = acc[j][r];
                cs[j] += (z >= 0.f) ? z : aslope * z;
            }
    }
#pragma unroll
    for (int j = 0; j < 4; ++j) {
        cs[j] += __shfl_xor(cs[j], 16, 64);   // reduce rows: quad bits only
        cs[j] += __shfl_xor(cs[j], 32, 64);
    }
    if (quad == 0)
#pragma unroll
        for (int j = 0; j < 4; ++j)
            partial[(size_t)((4 * w + j) * 16 + nl) * nb + blockIdx.x] = cs[j];
}

// ---------- K4: parallel partial reduce -> sum_h (one block per out dim) ----------
__global__ __launch_bounds__(256) void reduce_partials(
    const float* __restrict__ partial, int nb, float* __restrict__ sum_h)
{
    __shared__ float l[256];
    int d = blockIdx.x, tid = threadIdx.x;
    float s = 0.f;
    for (int i = tid; i < nb; i += 256)
        s += partial[(size_t)d * nb + i];
    l[tid] = s;
    __syncthreads();
    for (int o = 128; o > 0; o >>= 1) {
        if (tid < o) l[tid] += l[tid + o];
        __syncthreads();
    }
    if (tid == 0) sum_h[d] = l[0];
}

// ---------- K5: s = sigmoid(sum_h/N); v = w_bil @ s ----------
__global__ __launch_bounds__(256) void compute_v(
    const float* __restrict__ sum_h, const float* __restrict__ wbilf,
    float* __restrict__ v, float invN)
{
    __shared__ float s_lds[256];
    int t = threadIdx.x;
    float m = sum_h[t] * invN;
    s_lds[t] = 1.f / (1.f + expf(-m));
    __syncthreads();
    const float* wrow = wbilf + (size_t)t * 256;
    float acc = 0.f;
#pragma unroll 8
    for (int j = 0; j < 256; ++j)
        acc = fmaf(wrow[j], s_lds[j], acc);
    v[t] = acc;
}

// ---------- K6: GEMM + dot with v; W1 resident; LDS cross-wave reduce ----------
__global__ __launch_bounds__(256) void gemm_dp2(
    const short* __restrict__ aggx, const short* __restrict__ aggt,
    const short* __restrict__ w1, const float* __restrict__ paf,
    const float* __restrict__ v, const int* __restrict__ flag,
    void* __restrict__ outv, int ntiles, int N)
{
    __shared__ float dpbuf[4][T_TILES * 16];
    int tid = threadIdx.x;
    int w = tid >> 6, lane = tid & 63;
    int nl = lane & 15, quad = lane >> 4;
    const short* agg = blockIdx.y ? aggt : aggx;
    const short* brow = w1 + ((size_t)(4 * w) * 16 + nl) * 128 + quad * 8;
    bf16x8 bf[4][4];
#pragma unroll
    for (int j = 0; j < 4; ++j)
#pragma unroll
        for (int k = 0; k < 4; ++k)
            bf[j][k] = *(const bf16x8*)(brow + j * 2048 + k * 32);
    float vreg[4];
#pragma unroll
    for (int j = 0; j < 4; ++j) vreg[j] = v[(4 * w + j) * 16 + nl];
    float aslope = paf[0];
    int t0 = blockIdx.x * T_TILES;
    int nt = ntiles - t0; if (nt > T_TILES) nt = T_TILES;
    for (int i = 0; i < nt; ++i) {
        const short* arow = agg + ((size_t)(t0 + i) * 16 + nl) * 128 + quad * 8;
        bf16x8 af[4];
#pragma unroll
        for (int k = 0; k < 4; ++k) af[k] = *(const bf16x8*)(arow + k * 32);
        f32x4 acc[4];
#pragma unroll
        for (int j = 0; j < 4; ++j) acc[j] = (f32x4){0.f, 0.f, 0.f, 0.f};
#pragma unroll
        for (int k = 0; k < 4; ++k)
#pragma unroll
            for (int j = 0; j < 4; ++j)
                acc[j] = __builtin_amdgcn_mfma_f32_16x16x32_bf16(af[k], bf[j][k], acc[j], 0, 0, 0);
        float p[4] = {0.f, 0.f, 0.f, 0.f};
#pragma unroll
        for (int j = 0; j < 4; ++j)
#pragma unroll
            for (int r = 0; r < 4; ++r) {
                float z = acc[j][r];
                float h = (z >= 0.f) ? z : aslope * z;
                p[r] = fmaf(h, vreg[j], p[r]);
            }
#pragma unroll
        for (int r = 0; r < 4; ++r) {   // reduce over nl bits (16 cols of the slice)
            p[r] += __shfl_xor(p[r], 1, 64);
            p[r] += __shfl_xor(p[r], 2, 64);
            p[r] += __shfl_xor(p[r], 4, 64);
            p[r] += __shfl_xor(p[r], 8, 64);
        }
        if (nl == 0)
#pragma unroll
            for (int r = 0; r < 4; ++r)
                dpbuf[w][i * 16 + quad * 4 + r] = p[r];
    }
    __syncthreads();
    int nloc = nt * 16;
    int f = flag[0];
    for (int idx = tid; idx < nloc; idx += 256) {
        float s = dpbuf[0][idx] + dpbuf[1][idx] + dpbuf[2][idx] + dpbuf[3][idx];
        size_t o = (size_t)blockIdx.y * N + (size_t)t0 * 16 + idx;
        if (f) ((float*)outv)[o] = s;
        else   ((unsigned short*)outv)[o] = f2b(s);
    }
}

extern "C" void kernel_launch(void* const* d_in, const int* in_sizes, int n_in,
                              void* d_out, int out_size, void* d_ws, size_t ws_size,
                              hipStream_t stream) {
    const void* x    = d_in[0];
    const void* xt   = d_in[1];
    const void* vals = d_in[2];
    const int* row   = (const int*)d_in[3];
    const int* col   = (const int*)d_in[4];
    const void* w1   = d_in[5];
    const void* pa   = d_in[6];
    const void* wb   = d_in[7];

    const int N = in_sizes[0] / 128;
    const int E = in_sizes[2];
    const int ntiles = (N + 15) / 16;
    const int cs_blocks = (ntiles + T_TILES - 1) / T_TILES;

    char* ws = (char*)d_ws;
    size_t off = 0;
    auto alloc = [&](size_t bytes) { char* p = ws + off; off = (off + bytes + 255) & ~(size_t)255; return p; };
    int* row_ptr         = (int*)alloc((size_t)(N + 1) * 4);
    unsigned short* aggx = (unsigned short*)alloc((size_t)N * 128 * 2);
    unsigned short* aggt = (unsigned short*)alloc((size_t)N * 128 * 2);
    unsigned short* w1b  = (unsigned short*)alloc(32768 * 2);
    float* wbilf         = (float*)alloc(65536 * 4);
    float* partial       = (float*)alloc((size_t)cs_blocks * 256 * 4);
    float* sum_h         = (float*)alloc(256 * 4);
    float* vvec          = (float*)alloc(256 * 4);
    float* paf           = (float*)alloc(4);
    int* flag            = (int*)alloc(4);
    size_t xintBytes = (size_t)N * 256 * 2;   // interleaved x | x_tilde (bf16)
    bool big = (off + xintBytes + 512) <= ws_size;
    unsigned short* xint = nullptr;
    if (big) xint = (unsigned short*)alloc(xintBytes);

    detect_dtype<<<1, 256, 0, stream>>>((const unsigned int*)x, flag);

    int rb = (E + 1 + 255) / 256;
    int pb = 256;
    int total8 = (N * 128) / 8;
    int halfcb = big ? (total8 + 255) / 256 : 0;
    prep<<<rb + pb + 2 * halfcb, 256, 0, stream>>>(
        row, row_ptr, N, E, rb,
        w1, wb, pa, flag, w1b, wbilf, paf, pb,
        x, xt, xint, total8, halfcb);

    if (big) {
        spmm_dual3<<<(N + 3) / 4, 256, 0, stream>>>(xint, vals, col, row_ptr, flag,
                                                    aggx, aggt, N);
    } else {
        spmm_dual_legacy<<<(N + 3) / 4, 256, 0, stream>>>(x, xt, vals, col, row_ptr, flag,
                                                          aggx, aggt, N);
    }
    gemm_colsum3<<<cs_blocks, 256, 0, stream>>>(
        (const short*)aggx, (const short*)w1b, paf, partial, ntiles, cs_blocks);
    reduce_partials<<<256, 256, 0, stream>>>(partial, cs_blocks, sum_h);
    compute_v<<<1, 256, 0, stream>>>(sum_h, wbilf, vvec, 1.0f / (float)N);
    gemm_dp2<<<dim3(cs_blocks, 2), 256, 0, stream>>>(
        (const short*)aggx, (const short*)aggt, (const short*)w1b, paf, vvec, flag,
        d_out, ntiles, N);
}

// Round 6
// 335.725 us; speedup vs baseline: 1.2157x; 1.0144x over previous
//
#include <hip/hip_runtime.h>

// Inputs are f32 (verified: R2-R5 passed via runtime-detect f32 path; reference
// declares float32 and output absmax matched at f32 write-back). bf16 staging
// internally; f32 accumulate; f32 out.

// ---------- bf16 bit helpers ----------
__device__ __forceinline__ float b2f(unsigned short s) {
    union { unsigned int u; float f; } c; c.u = ((unsigned int)s) << 16; return c.f;
}
__device__ __forceinline__ unsigned short f2b(float f) {
    union { float f; unsigned int u; } c; c.f = f;
    unsigned int u = c.u;
    unsigned int r = u + 0x7FFFu + ((u >> 16) & 1u);   // RNE
    return (unsigned short)(r >> 16);
}
__device__ __forceinline__ unsigned int pack2(float lo, float hi) {
    return ((unsigned int)f2b(hi) << 16) | f2b(lo);
}
__device__ __forceinline__ void fma8(float* a, float v, uint4 w) {
    a[0] = fmaf(v, b2f((unsigned short)w.x), a[0]);
    a[1] = fmaf(v, b2f((unsigned short)(w.x >> 16)), a[1]);
    a[2] = fmaf(v, b2f((unsigned short)w.y), a[2]);
    a[3] = fmaf(v, b2f((unsigned short)(w.y >> 16)), a[3]);
    a[4] = fmaf(v, b2f((unsigned short)w.z), a[4]);
    a[5] = fmaf(v, b2f((unsigned short)(w.z >> 16)), a[5]);
    a[6] = fmaf(v, b2f((unsigned short)w.w), a[6]);
    a[7] = fmaf(v, b2f((unsigned short)(w.w >> 16)), a[7]);
}

typedef __attribute__((ext_vector_type(8))) short bf16x8;
typedef __attribute__((ext_vector_type(4))) float f32x4;

#define T_TILES 10

// ---------- K1: fused prep: rowptr | W1 -> bf16 | x/x_tilde -> interleaved bf16 ----------
// xint layout: node row = 512 B: [x 128 bf16][x_tilde 128 bf16]
__global__ __launch_bounds__(256) void prep(
    const int* __restrict__ row, int* __restrict__ rp, int n, int e, int rb,
    const float* __restrict__ w1, unsigned short* __restrict__ w1b, int pb,
    const float* __restrict__ x, const float* __restrict__ xt,
    unsigned short* __restrict__ xint, int total8, int halfcb)
{
    int b = blockIdx.x, tid = threadIdx.x;
    if (b < rb) {                                   // --- build row_ptr ---
        int i = b * 256 + tid;
        if (i > e) return;
        if (i == 0) {
            int r1 = row[0];
            for (int rr = 0; rr <= r1; ++rr) rp[rr] = 0;
        } else if (i == e) {
            int r0 = row[e - 1];
            for (int rr = r0 + 1; rr <= n; ++rr) rp[rr] = e;
        } else {
            int r0 = row[i - 1], r1 = row[i];
            for (int rr = r0 + 1; rr <= r1; ++rr) rp[rr] = i;
        }
    } else if (b < rb + pb) {                       // --- W1 -> bf16 ---
        int i = (b - rb) * 256 + tid;               // 0..32767
        if (i < 32768) w1b[i] = f2b(w1[i]);
    } else {                                        // --- x conversion (interleaved) ---
        int cb = b - rb - pb;
        int which = (cb >= halfcb) ? 1 : 0;
        int i = (cb - which * halfcb) * 256 + tid;  // 8-elem chunk index
        if (i >= total8) return;
        const float* s = which ? xt : x;
        int node = i >> 4, sub = i & 15;
        const float4* p = (const float4*)s + (size_t)i * 2;
        float4 a = p[0], bb = p[1];
        uint4 o;
        o.x = pack2(a.x, a.y);  o.y = pack2(a.z, a.w);
        o.z = pack2(bb.x, bb.y); o.w = pack2(bb.z, bb.w);
        *(uint4*)(xint + (size_t)node * 256 + which * 128 + sub * 8) = o;
    }
}

// ---------- K2: dual SpMM; col/vals preloaded per 64-edge chunk, 16 edges/iter ----------
// lane = g*16 + l: group g handles edges {base+4u+g}, lane l handles dims [8l,8l+8)
__global__ __launch_bounds__(256) void spmm_dual4(
    const unsigned short* __restrict__ xint, const float* __restrict__ vals,
    const int* __restrict__ col, const int* __restrict__ row_ptr,
    unsigned short* __restrict__ aggx, unsigned short* __restrict__ aggt, int n)
{
    int wave = threadIdx.x >> 6;
    int lane = threadIdx.x & 63;
    int g = lane >> 4, l = lane & 15;
    int r = blockIdx.x * 4 + wave;
    if (r >= n) return;
    int e0 = row_ptr[r], e1 = row_ptr[r + 1];
    float ax[8], at[8];
#pragma unroll
    for (int d = 0; d < 8; ++d) { ax[d] = 0.f; at[d] = 0.f; }
    for (int chunk = e0; chunk < e1; chunk += 64) {
        int m = e1 - chunk; if (m > 64) m = 64;     // edges in this chunk
        int ce = chunk + (lane < m ? lane : m - 1); // coalesced preload (clamped)
        int cc = col[ce];
        float cv = (lane < m) ? vals[ce] : 0.f;
        for (int base = 0; base < m; base += 16) {
            uint4 xw[4], tw[4];
            float fv[4];
#pragma unroll
            for (int u = 0; u < 4; ++u) {
                int idx = base + 4 * u + g;
                int idc = idx < m ? idx : m - 1;    // clamp: duplicate line is cache-hot
                int c  = __shfl(cc, idc, 64);
                float v = __shfl(cv, idc, 64);
                fv[u] = (idx < m) ? v : 0.f;
                const uint4* p = (const uint4*)(xint + (size_t)c * 256);
                xw[u] = p[l];
                tw[u] = p[16 + l];
            }
#pragma unroll
            for (int u = 0; u < 4; ++u) { fma8(ax, fv[u], xw[u]); fma8(at, fv[u], tw[u]); }
        }
    }
#pragma unroll
    for (int d = 0; d < 8; ++d) {
        ax[d] += __shfl_xor(ax[d], 16, 64);
        ax[d] += __shfl_xor(ax[d], 32, 64);
        at[d] += __shfl_xor(at[d], 16, 64);
        at[d] += __shfl_xor(at[d], 32, 64);
    }
    if (g == 0) {
        uint4 o;
        o.x = pack2(ax[0], ax[1]); o.y = pack2(ax[2], ax[3]);
        o.z = pack2(ax[4], ax[5]); o.w = pack2(ax[6], ax[7]);
        ((uint4*)(aggx + (size_t)r * 128))[l] = o;
    } else if (g == 1) {
        uint4 o;
        o.x = pack2(at[0], at[1]); o.y = pack2(at[2], at[3]);
        o.z = pack2(at[4], at[5]); o.w = pack2(at[6], at[7]);
        ((uint4*)(aggt + (size_t)r * 128))[l] = o;
    }
}

// ---------- K3: GEMM + colsum; W1 resident; transposed atomic-free partials ----------
// C/D layout: col = nl, row = quad*4 + r. Column sum => sum over r, then quad bits.
// partial layout: [out_dim 256][block nb]  (coalesced for the reducer)
__global__ __launch_bounds__(256) void gemm_colsum3(
    const short* __restrict__ aggb, const short* __restrict__ w1,
    const float* __restrict__ pa, float* __restrict__ partial, int ntiles, int nb)
{
    int tid = threadIdx.x;
    int w = tid >> 6, lane = tid & 63;
    int nl = lane & 15, quad = lane >> 4;
    const short* brow = w1 + ((size_t)(4 * w) * 16 + nl) * 128 + quad * 8;
    bf16x8 bf[4][4];
#pragma unroll
    for (int j = 0; j < 4; ++j)
#pragma unroll
        for (int k = 0; k < 4; ++k)
            bf[j][k] = *(const bf16x8*)(brow + j * 2048 + k * 32);
    float aslope = pa[0];
    float cs[4] = {0.f, 0.f, 0.f, 0.f};
    int t0 = blockIdx.x * T_TILES;
    int nt = ntiles - t0; if (nt > T_TILES) nt = T_TILES;
    for (int i = 0; i < nt; ++i) {
        const short* arow = aggb + ((size_t)(t0 + i) * 16 + nl) * 128 + quad * 8;
        bf16x8 af[4];
#pragma unroll
        for (int k = 0; k < 4; ++k) af[k] = *(const bf16x8*)(arow + k * 32);
        f32x4 acc[4];
#pragma unroll
        for (int j = 0; j < 4; ++j) acc[j] = (f32x4){0.f, 0.f, 0.f, 0.f};
#pragma unroll
        for (int k = 0; k < 4; ++k)
#pragma unroll
            for (int j = 0; j < 4; ++j)
                acc[j] = __builtin_amdgcn_mfma_f32_16x16x32_bf16(af[k], bf[j][k], acc[j], 0, 0, 0);
#pragma unroll
        for (int j = 0; j < 4; ++j)
#pragma unroll
            for (int r = 0; r < 4; ++r) {
                float z = acc[j][r];
                cs[j] += (z >= 0.f) ? z : aslope * z;
            }
    }
#pragma unroll
    for (int j = 0; j < 4; ++j) {
        cs[j] += __shfl_xor(cs[j], 16, 64);   // reduce rows: quad bits only
        cs[j] += __shfl_xor(cs[j], 32, 64);
    }
    if (quad == 0)
#pragma unroll
        for (int j = 0; j < 4; ++j)
            partial[(size_t)((4 * w + j) * 16 + nl) * nb + blockIdx.x] = cs[j];
}

// ---------- K4: reduce partials + sigmoid -> s (one block per out dim) ----------
__global__ __launch_bounds__(256) void reduce_sig(
    const float* __restrict__ partial, int nb, float* __restrict__ s_out, float invN)
{
    __shared__ float l[256];
    int d = blockIdx.x, tid = threadIdx.x;
    float s = 0.f;
    for (int i = tid; i < nb; i += 256)
        s += partial[(size_t)d * nb + i];
    l[tid] = s;
    __syncthreads();
    for (int o = 128; o > 0; o >>= 1) {
        if (tid < o) l[tid] += l[tid + o];
        __syncthreads();
    }
    if (tid == 0) s_out[d] = 1.f / (1.f + expf(-l[0] * invN));
}

// ---------- K5: v = w_bil @ s (single block) ----------
__global__ __launch_bounds__(256) void compute_v(
    const float* __restrict__ s_in, const float* __restrict__ wbil,
    float* __restrict__ v)
{
    __shared__ float s_lds[256];
    int t = threadIdx.x;
    s_lds[t] = s_in[t];
    __syncthreads();
    const float* wrow = wbil + (size_t)t * 256;
    float acc = 0.f;
#pragma unroll 8
    for (int j = 0; j < 256; ++j)
        acc = fmaf(wrow[j], s_lds[j], acc);
    v[t] = acc;
}

// ---------- K6: GEMM + dot with v; W1 resident; LDS cross-wave reduce ----------
__global__ __launch_bounds__(256) void gemm_dp2(
    const short* __restrict__ aggx, const short* __restrict__ aggt,
    const short* __restrict__ w1, const float* __restrict__ pa,
    const float* __restrict__ v, float* __restrict__ out, int ntiles, int N)
{
    __shared__ float dpbuf[4][T_TILES * 16];
    int tid = threadIdx.x;
    int w = tid >> 6, lane = tid & 63;
    int nl = lane & 15, quad = lane >> 4;
    const short* agg = blockIdx.y ? aggt : aggx;
    const short* brow = w1 + ((size_t)(4 * w) * 16 + nl) * 128 + quad * 8;
    bf16x8 bf[4][4];
#pragma unroll
    for (int j = 0; j < 4; ++j)
#pragma unroll
        for (int k = 0; k < 4; ++k)
            bf[j][k] = *(const bf16x8*)(brow + j * 2048 + k * 32);
    float vreg[4];
#pragma unroll
    for (int j = 0; j < 4; ++j) vreg[j] = v[(4 * w + j) * 16 + nl];
    float aslope = pa[0];
    int t0 = blockIdx.x * T_TILES;
    int nt = ntiles - t0; if (nt > T_TILES) nt = T_TILES;
    for (int i = 0; i < nt; ++i) {
        const short* arow = agg + ((size_t)(t0 + i) * 16 + nl) * 128 + quad * 8;
        bf16x8 af[4];
#pragma unroll
        for (int k = 0; k < 4; ++k) af[k] = *(const bf16x8*)(arow + k * 32);
        f32x4 acc[4];
#pragma unroll
        for (int j = 0; j < 4; ++j) acc[j] = (f32x4){0.f, 0.f, 0.f, 0.f};
#pragma unroll
        for (int k = 0; k < 4; ++k)
#pragma unroll
            for (int j = 0; j < 4; ++j)
                acc[j] = __builtin_amdgcn_mfma_f32_16x16x32_bf16(af[k], bf[j][k], acc[j], 0, 0, 0);
        float p[4] = {0.f, 0.f, 0.f, 0.f};
#pragma unroll
        for (int j = 0; j < 4; ++j)
#pragma unroll
            for (int r = 0; r < 4; ++r) {
                float z = acc[j][r];
                float h = (z >= 0.f) ? z : aslope * z;
                p[r] = fmaf(h, vreg[j], p[r]);
            }
#pragma unroll
        for (int r = 0; r < 4; ++r) {   // reduce over nl bits (16 cols of the slice)
            p[r] += __shfl_xor(p[r], 1, 64);
            p[r] += __shfl_xor(p[r], 2, 64);
            p[r] += __shfl_xor(p[r], 4, 64);
            p[r] += __shfl_xor(p[r], 8, 64);
        }
        if (nl == 0)
#pragma unroll
            for (int r = 0; r < 4; ++r)
                dpbuf[w][i * 16 + quad * 4 + r] = p[r];
    }
    __syncthreads();
    int nloc = nt * 16;
    for (int idx = tid; idx < nloc; idx += 256) {
        float s = dpbuf[0][idx] + dpbuf[1][idx] + dpbuf[2][idx] + dpbuf[3][idx];
        out[(size_t)blockIdx.y * N + (size_t)t0 * 16 + idx] = s;
    }
}

extern "C" void kernel_launch(void* const* d_in, const int* in_sizes, int n_in,
                              void* d_out, int out_size, void* d_ws, size_t ws_size,
                              hipStream_t stream) {
    const float* x    = (const float*)d_in[0];
    const float* xt   = (const float*)d_in[1];
    const float* vals = (const float*)d_in[2];
    const int* row    = (const int*)d_in[3];
    const int* col    = (const int*)d_in[4];
    const float* w1   = (const float*)d_in[5];
    const float* pa   = (const float*)d_in[6];
    const float* wb   = (const float*)d_in[7];

    const int N = in_sizes[0] / 128;
    const int E = in_sizes[2];
    const int ntiles = (N + 15) / 16;
    const int cs_blocks = (ntiles + T_TILES - 1) / T_TILES;

    char* ws = (char*)d_ws;
    size_t off = 0;
    auto alloc = [&](size_t bytes) { char* p = ws + off; off = (off + bytes + 255) & ~(size_t)255; return p; };
    int* row_ptr         = (int*)alloc((size_t)(N + 1) * 4);
    unsigned short* aggx = (unsigned short*)alloc((size_t)N * 128 * 2);
    unsigned short* aggt = (unsigned short*)alloc((size_t)N * 128 * 2);
    unsigned short* w1b  = (unsigned short*)alloc(32768 * 2);
    float* partial       = (float*)alloc((size_t)cs_blocks * 256 * 4);
    float* svec          = (float*)alloc(256 * 4);
    float* vvec          = (float*)alloc(256 * 4);
    unsigned short* xint = (unsigned short*)alloc((size_t)N * 256 * 2);  // x|xt interleaved bf16

    int rb = (E + 1 + 255) / 256;
    int pb = 128;
    int total8 = (N * 128) / 8;
    int halfcb = (total8 + 255) / 256;
    prep<<<rb + pb + 2 * halfcb, 256, 0, stream>>>(
        row, row_ptr, N, E, rb, w1, w1b, pb, x, xt, xint, total8, halfcb);

    spmm_dual4<<<(N + 3) / 4, 256, 0, stream>>>(xint, vals, col, row_ptr, aggx, aggt, N);

    gemm_colsum3<<<cs_blocks, 256, 0, stream>>>(
        (const short*)aggx, (const short*)w1b, pa, partial, ntiles, cs_blocks);
    reduce_sig<<<256, 256, 0, stream>>>(partial, cs_blocks, svec, 1.0f / (float)N);
    compute_v<<<1, 256, 0, stream>>>(svec, wb, vvec);
    gemm_dp2<<<dim3(cs_blocks, 2), 256, 0, stream>>>(
        (const short*)aggx, (const short*)aggt, (const short*)w1b, pa, vvec,
        (float*)d_out, ntiles, N);
}